// Round 2
// baseline (833.510 us; speedup 1.0000x reference)
//
#include <hip/hip_runtime.h>

typedef __bf16 bf16x8 __attribute__((ext_vector_type(8)));
typedef __bf16 bf16x2_t __attribute__((ext_vector_type(2)));
typedef float floatx4 __attribute__((ext_vector_type(4)));
typedef unsigned short ushort_t;
typedef unsigned short ushortx8 __attribute__((ext_vector_type(8)));
typedef unsigned int uintx2 __attribute__((ext_vector_type(2)));
typedef unsigned int uintx4 __attribute__((ext_vector_type(4)));

// fp32 -> bf16 round-to-nearest-even (fallback path)
__device__ inline ushort_t f2bf(float f) {
    union { float f; unsigned int u; } v; v.f = f;
    unsigned int u = v.u;
    return (ushort_t)((u + 0x7FFFu + ((u >> 16) & 1u)) >> 16);
}

__device__ inline unsigned int pk_bf16(float a, float b) {
#if __has_builtin(__builtin_amdgcn_cvt_pk_bf16_f32)
    bf16x2_t r = __builtin_amdgcn_cvt_pk_bf16_f32(a, b);
    union { bf16x2_t v; unsigned int u; } c; c.v = r; return c.u;
#else
    return (unsigned int)f2bf(a) | ((unsigned int)f2bf(b) << 16);
#endif
}

__device__ inline float fast_exp2(float z) {
#if __has_builtin(__builtin_amdgcn_exp2f)
    return __builtin_amdgcn_exp2f(z);
#else
    return __expf(z * 0.6931471805599453f);
#endif
}

__device__ inline float frsq(float a) {
#if __has_builtin(__builtin_amdgcn_rsqf)
    return __builtin_amdgcn_rsqf(a);
#else
    return rsqrtf(a);
#endif
}

// tanh-form GELU via hw exp2/rcp: x * e/(e+1), e = exp(2*0.7978845608*(x + 0.044715 x^3))
__device__ inline float gelu_f(float x) {
    float x2 = x * x;
    float z  = x * (2.302023914f + 0.1029480874f * x2);   // 2*log2(e)*0.79788456*(1+0.044715 x^2)
    float e  = fast_exp2(z);
    float r  = __builtin_amdgcn_rcpf(e + 1.0f);
    return x - x * r;                                     // = x * e/(e+1)
}

// ---------------------------------------------------------------------------
// Pack W1/W2/W3 (fp32 row-major [K][N]) into bf16 MFMA A-operand fragments
// (lane holds W^T[feat=lane&15][k=8*(lane>>4)+j] = W[k][feat]), laid out
// ks-major per wave chunk so the main loop streams contiguous memory:
//  L1: [m][w(4)][ks(12)][ct(6)][lane(64)][8]  at 0       (294912 elems)
//  L2: [m][w(4)][ks(12)][ct(3)][lane(64)][8]  at 294912  (147456 elems)
//  L3: [m][g(2)][ks(6)][ct(3)][lane(64)][8]   at 442368  (36864 elems)
// ---------------------------------------------------------------------------
__global__ __launch_bounds__(256) void pack_weights(
    const float* __restrict__ W1, const float* __restrict__ W2,
    const float* __restrict__ W3, ushort_t* __restrict__ wsp)
{
    int g = blockIdx.x * 256 + threadIdx.x;
    if (g >= 59904) return;
    const float* src; int N, n, kbase; ushort_t* dst;
    if (g < 36864) {                       // W1: K=384,N=384
        int s = g;
        int m = s / 18432, r = s % 18432;
        int w = r / 4608; r %= 4608;
        int ks = r / 384; r %= 384;
        int ct = r / 64; int lane = r % 64;
        int q = lane >> 4, l16 = lane & 15;
        src = W1 + m * 147456; N = 384;
        n = 96 * w + 16 * ct + l16;
        kbase = 32 * ks + 8 * q;
        dst = wsp + (size_t)g * 8;
    } else if (g < 55296) {                // W2: K=384,N=192
        int t = g - 36864;
        int m = t / 9216, r = t % 9216;
        int w = r / 2304; r %= 2304;
        int ks = r / 192; r %= 192;
        int ct = r / 64; int lane = r % 64;
        int q = lane >> 4, l16 = lane & 15;
        src = W2 + m * 73728; N = 192;
        n = 48 * w + 16 * ct + l16;
        kbase = 32 * ks + 8 * q;
        dst = wsp + 294912 + (size_t)t * 8;
    } else {                               // W3: K=192,N=96
        int u = g - 55296;
        int m = u / 2304, r = u % 2304;
        int gg = r / 1152; r %= 1152;
        int ks = r / 192; r %= 192;
        int ct = r / 64; int lane = r % 64;
        int q = lane >> 4, l16 = lane & 15;
        src = W3 + m * 18432; N = 96;
        n = 16 * (3 * gg + ct) + l16;
        kbase = 32 * ks + 8 * q;
        dst = wsp + 442368 + (size_t)u * 8;
    }
    ushortx8 o;
    #pragma unroll
    for (int j = 0; j < 8; ++j) o[j] = f2bf(src[(size_t)(kbase + j) * N + n]);
    *(ushortx8*)dst = o;
}

// ---------------------------------------------------------------------------
// Fused LN -> L1(384x384)+GELU -> L2(384x192)+GELU -> L3(192x96)+GELU
//       -> L4(96x2) -> log_softmax.  Block = 32 rows, 256 thr (4 waves).
// MFMA operands swapped (W as A, activations as B): D[row=4q+i]=feature,
// D[col=l16]=x-row  ->  vectorized b64 epilogue stores, float4 bias broadcast.
// ---------------------------------------------------------------------------
__global__ __launch_bounds__(256, 3) void fused_mlp(
    const float* __restrict__ x, const float* __restrict__ ln_g, const float* __restrict__ ln_b,
    const float* __restrict__ b1, const float* __restrict__ b2, const float* __restrict__ b3,
    const float* __restrict__ W4, const float* __restrict__ b4,
    const ushort_t* __restrict__ wsp, float* __restrict__ out)
{
    __shared__ __align__(16) ushort_t sA[12544];   // 32 x stride392 (reused 32 x stride200)
    __shared__ __align__(16) ushort_t sH[12544];   // 32 x stride392 (reused 32 x stride104)
    __shared__ __align__(16) float    sF[864];     // b1[0,384) b2[384,576) b3[576,672) W4T[672,864)

    const int tid = threadIdx.x;
    const int w = tid >> 6, lane = tid & 63, q = lane >> 4, l16 = lane & 15;
    const int bid = blockIdx.x;
    const int m  = bid >> 12;
    const int rb = bid & 4095;
    const size_t row0 = (size_t)m * 131072 + (size_t)rb * 32;

    // ---- stage biases + W4^T ----
    {
        const float* pb1 = b1 + m * 384;
        const float* pb2 = b2 + m * 192;
        const float* pb3 = b3 + m * 96;
        const float* pW4 = W4 + m * 192;
        for (int i = tid; i < 384; i += 256) sF[i] = pb1[i];
        if (tid < 192) sF[384 + tid] = pb2[tid];
        if (tid < 96)  sF[576 + tid] = pb3[tid];
        if (tid < 192) sF[672 + (tid & 1) * 96 + (tid >> 1)] = pW4[tid]; // W4T[cl][k]
    }

    // ---- LayerNorm: 8 threads/row, 48 cols each; bf16 -> sA stride 392 ----
    {
        const int row = tid >> 3, j = tid & 7;
        const floatx4* xv = (const floatx4*)(x + (row0 + row) * 384);
        const floatx4* gv = (const floatx4*)(ln_g + m * 384);
        const floatx4* bv = (const floatx4*)(ln_b + m * 384);
        floatx4 v[12];
        float s = 0.f, s2 = 0.f;
        #pragma unroll
        for (int i = 0; i < 12; ++i) {
            v[i] = __builtin_nontemporal_load(&xv[j * 12 + i]);
            #pragma unroll
            for (int e = 0; e < 4; ++e) { s += v[i][e]; s2 = fmaf(v[i][e], v[i][e], s2); }
        }
        s  += __shfl_xor(s, 1);  s  += __shfl_xor(s, 2);  s  += __shfl_xor(s, 4);
        s2 += __shfl_xor(s2, 1); s2 += __shfl_xor(s2, 2); s2 += __shfl_xor(s2, 4);
        const float mu   = s * (1.0f / 384.0f);
        const float var  = fmaf(s2, 1.0f / 384.0f, -mu * mu);
        const float rstd = frsq(var + 1e-5f);
        #pragma unroll
        for (int h = 0; h < 6; ++h) {
            floatx4 ga = gv[j * 12 + 2 * h], gb = gv[j * 12 + 2 * h + 1];
            floatx4 ca = bv[j * 12 + 2 * h], cb = bv[j * 12 + 2 * h + 1];
            float y[8];
            #pragma unroll
            for (int e = 0; e < 4; ++e) y[e]     = (v[2*h][e]   - mu) * rstd * ga[e] + ca[e];
            #pragma unroll
            for (int e = 0; e < 4; ++e) y[4 + e] = (v[2*h+1][e] - mu) * rstd * gb[e] + cb[e];
            uintx4 st = { pk_bf16(y[0], y[1]), pk_bf16(y[2], y[3]),
                          pk_bf16(y[4], y[5]), pk_bf16(y[6], y[7]) };
            *(uintx4*)&sA[row * 392 + j * 48 + h * 8] = st;
        }
    }

    // ---- L1 W-frag prefetch (ks=0,1) before barrier: latency hides in wait ----
    const bf16x8* Wv1 = (const bf16x8*)(wsp + (m * 4 + w) * 36864) + lane;
    bf16x8 wb1[2][6];
    #pragma unroll
    for (int c = 0; c < 6; ++c) wb1[0][c] = Wv1[c * 64];
    #pragma unroll
    for (int c = 0; c < 6; ++c) wb1[1][c] = Wv1[(6 + c) * 64];

    __syncthreads();

    const floatx4 vzero = {0.f, 0.f, 0.f, 0.f};

    // ---- Layer 1: wave w -> features [96w,96w+96) for all 32 rows ----
    floatx4 acc1[2][6];
    #pragma unroll
    for (int rt = 0; rt < 2; ++rt)
        #pragma unroll
        for (int ct = 0; ct < 6; ++ct) acc1[rt][ct] = vzero;
    #pragma unroll
    for (int ks = 0; ks < 12; ++ks) {
        bf16x8 a0 = *(const bf16x8*)&sA[l16        * 392 + 32 * ks + 8 * q];
        bf16x8 a1 = *(const bf16x8*)&sA[(16 + l16) * 392 + 32 * ks + 8 * q];
        #pragma unroll
        for (int c = 0; c < 6; ++c) {
            acc1[0][c] = __builtin_amdgcn_mfma_f32_16x16x32_bf16(wb1[ks & 1][c], a0, acc1[0][c], 0, 0, 0);
            acc1[1][c] = __builtin_amdgcn_mfma_f32_16x16x32_bf16(wb1[ks & 1][c], a1, acc1[1][c], 0, 0, 0);
        }
        if (ks < 10) {
            #pragma unroll
            for (int c = 0; c < 6; ++c) wb1[ks & 1][c] = Wv1[((ks + 2) * 6 + c) * 64];
        }
    }

    // ---- prefetch L2 W-frags (ks=0,1) before epilogue+barrier ----
    const bf16x8* Wv2 = (const bf16x8*)(wsp + 294912 + (m * 4 + w) * 18432) + lane;
    bf16x8 wb2[2][3];
    #pragma unroll
    for (int c = 0; c < 3; ++c) wb2[0][c] = Wv2[c * 64];
    #pragma unroll
    for (int c = 0; c < 3; ++c) wb2[1][c] = Wv2[(3 + c) * 64];

    // ---- L1 epilogue: bias + GELU -> sH stride 392 (b64 stores) ----
    #pragma unroll
    for (int ct = 0; ct < 6; ++ct) {
        const int f = 96 * w + 16 * ct + 4 * q;
        const floatx4 bb = *(const floatx4*)&sF[f];
        #pragma unroll
        for (int rt = 0; rt < 2; ++rt) {
            float g0 = gelu_f(acc1[rt][ct][0] + bb[0]);
            float g1 = gelu_f(acc1[rt][ct][1] + bb[1]);
            float g2 = gelu_f(acc1[rt][ct][2] + bb[2]);
            float g3 = gelu_f(acc1[rt][ct][3] + bb[3]);
            uintx2 u = { pk_bf16(g0, g1), pk_bf16(g2, g3) };
            *(uintx2*)&sH[(16 * rt + l16) * 392 + f] = u;
        }
    }
    __syncthreads();

    // ---- Layer 2: wave w -> features [48w,48w+48) ----
    floatx4 acc2[2][3];
    #pragma unroll
    for (int rt = 0; rt < 2; ++rt)
        #pragma unroll
        for (int ct = 0; ct < 3; ++ct) acc2[rt][ct] = vzero;
    #pragma unroll
    for (int ks = 0; ks < 12; ++ks) {
        bf16x8 a0 = *(const bf16x8*)&sH[l16        * 392 + 32 * ks + 8 * q];
        bf16x8 a1 = *(const bf16x8*)&sH[(16 + l16) * 392 + 32 * ks + 8 * q];
        #pragma unroll
        for (int c = 0; c < 3; ++c) {
            acc2[0][c] = __builtin_amdgcn_mfma_f32_16x16x32_bf16(wb2[ks & 1][c], a0, acc2[0][c], 0, 0, 0);
            acc2[1][c] = __builtin_amdgcn_mfma_f32_16x16x32_bf16(wb2[ks & 1][c], a1, acc2[1][c], 0, 0, 0);
        }
        if (ks < 10) {
            #pragma unroll
            for (int c = 0; c < 3; ++c) wb2[ks & 1][c] = Wv2[((ks + 2) * 3 + c) * 64];
        }
    }

    // ---- prefetch L3 W-frags ----
    const int g3i = w & 1, rt3 = w >> 1;
    const bf16x8* Wv3 = (const bf16x8*)(wsp + 442368 + (m * 2 + g3i) * 9216) + lane;
    bf16x8 wb3[2][3];
    #pragma unroll
    for (int c = 0; c < 3; ++c) wb3[0][c] = Wv3[c * 64];
    #pragma unroll
    for (int c = 0; c < 3; ++c) wb3[1][c] = Wv3[(3 + c) * 64];

    // ---- L2 epilogue -> sA stride 200 ----
    #pragma unroll
    for (int ct = 0; ct < 3; ++ct) {
        const int f = 48 * w + 16 * ct + 4 * q;
        const floatx4 bb = *(const floatx4*)&sF[384 + f];
        #pragma unroll
        for (int rt = 0; rt < 2; ++rt) {
            float g0 = gelu_f(acc2[rt][ct][0] + bb[0]);
            float g1 = gelu_f(acc2[rt][ct][1] + bb[1]);
            float g2 = gelu_f(acc2[rt][ct][2] + bb[2]);
            float g3 = gelu_f(acc2[rt][ct][3] + bb[3]);
            uintx2 u = { pk_bf16(g0, g1), pk_bf16(g2, g3) };
            *(uintx2*)&sA[(16 * rt + l16) * 200 + f] = u;
        }
    }
    __syncthreads();

    // ---- Layer 3: wave -> row-tile rt3, feature-group g3i (48 feats) ----
    floatx4 acc3[3];
    #pragma unroll
    for (int ct = 0; ct < 3; ++ct) acc3[ct] = vzero;
    #pragma unroll
    for (int ks = 0; ks < 6; ++ks) {
        bf16x8 a = *(const bf16x8*)&sA[(16 * rt3 + l16) * 200 + 32 * ks + 8 * q];
        #pragma unroll
        for (int c = 0; c < 3; ++c)
            acc3[c] = __builtin_amdgcn_mfma_f32_16x16x32_bf16(wb3[ks & 1][c], a, acc3[c], 0, 0, 0);
        if (ks < 4) {
            #pragma unroll
            for (int c = 0; c < 3; ++c) wb3[ks & 1][c] = Wv3[((ks + 2) * 3 + c) * 64];
        }
    }

    // ---- L3 epilogue -> sH stride 104 ----
    #pragma unroll
    for (int ct = 0; ct < 3; ++ct) {
        const int f = 16 * (3 * g3i + ct) + 4 * q;
        const floatx4 bb = *(const floatx4*)&sF[576 + f];
        float g0 = gelu_f(acc3[ct][0] + bb[0]);
        float g1 = gelu_f(acc3[ct][1] + bb[1]);
        float g2 = gelu_f(acc3[ct][2] + bb[2]);
        float g3 = gelu_f(acc3[ct][3] + bb[3]);
        uintx2 u = { pk_bf16(g0, g1), pk_bf16(g2, g3) };
        *(uintx2*)&sH[(16 * rt3 + l16) * 104 + f] = u;
    }
    __syncthreads();

    // ---- Layer 4: [32x96]@[96x2] + log_softmax; 128 threads, split-K ----
    if (tid < 128) {
        const int cl = tid & 1, kh = (tid >> 1) & 1, row = tid >> 2;
        const float* wv = &sF[672 + cl * 96 + kh * 48];
        float p = 0.f;
        #pragma unroll
        for (int kk = 0; kk < 6; ++kk) {
            bf16x8 h = *(const bf16x8*)&sH[row * 104 + kh * 48 + kk * 8];
            const floatx4 wa = *(const floatx4*)&wv[kk * 8];
            const floatx4 wb = *(const floatx4*)&wv[kk * 8 + 4];
            p += (float)h[0] * wa[0] + (float)h[1] * wa[1] + (float)h[2] * wa[2] + (float)h[3] * wa[3]
               + (float)h[4] * wb[0] + (float)h[5] * wb[1] + (float)h[6] * wb[2] + (float)h[7] * wb[3];
        }
        p += __shfl_xor(p, 2);                  // combine K-halves
        const float logit = p + b4[m * 2 + cl];
        const float other = __shfl_xor(logit, 1);
        const float mx = fmaxf(logit, other);
        const float z  = __expf(logit - mx) + __expf(other - mx);
        const float res = logit - mx - __logf(z);
        if (kh == 0) __builtin_nontemporal_store(res, &out[(row0 + row) * 2 + cl]);
    }
}

extern "C" void kernel_launch(void* const* d_in, const int* in_sizes, int n_in,
                              void* d_out, int out_size, void* d_ws, size_t ws_size,
                              hipStream_t stream)
{
    const float* x    = (const float*)d_in[0];
    const float* ln_g = (const float*)d_in[1];
    const float* ln_b = (const float*)d_in[2];
    const float* W1   = (const float*)d_in[3];
    const float* b1   = (const float*)d_in[4];
    const float* W2   = (const float*)d_in[5];
    const float* b2   = (const float*)d_in[6];
    const float* W3   = (const float*)d_in[7];
    const float* b3   = (const float*)d_in[8];
    const float* W4   = (const float*)d_in[9];
    const float* b4   = (const float*)d_in[10];
    float* out = (float*)d_out;
    ushort_t* wsp = (ushort_t*)d_ws;   // 958,464 B packed bf16 weights

    pack_weights<<<234, 256, 0, stream>>>(W1, W2, W3, wsp);
    fused_mlp<<<8192, 256, 0, stream>>>(x, ln_g, ln_b, b1, b2, b3, W4, b4, wsp, out);
}

// Round 3
// 670.099 us; speedup vs baseline: 1.2439x; 1.2439x over previous
//
#include <hip/hip_runtime.h>

typedef __bf16 bf16x8 __attribute__((ext_vector_type(8)));
typedef __bf16 bf16x2_t __attribute__((ext_vector_type(2)));
typedef float floatx4 __attribute__((ext_vector_type(4)));
typedef unsigned short ushort_t;
typedef unsigned short ushortx8 __attribute__((ext_vector_type(8)));
typedef unsigned int uintx2 __attribute__((ext_vector_type(2)));
typedef unsigned int uintx4 __attribute__((ext_vector_type(4)));

__device__ inline ushort_t f2bf(float f) {
    union { float f; unsigned int u; } v; v.f = f;
    unsigned int u = v.u;
    return (ushort_t)((u + 0x7FFFu + ((u >> 16) & 1u)) >> 16);
}

__device__ inline unsigned int pk_bf16(float a, float b) {
#if __has_builtin(__builtin_amdgcn_cvt_pk_bf16_f32)
    bf16x2_t r = __builtin_amdgcn_cvt_pk_bf16_f32(a, b);
    union { bf16x2_t v; unsigned int u; } c; c.v = r; return c.u;
#else
    return (unsigned int)f2bf(a) | ((unsigned int)f2bf(b) << 16);
#endif
}

__device__ inline float fast_exp2(float z) {
#if __has_builtin(__builtin_amdgcn_exp2f)
    return __builtin_amdgcn_exp2f(z);
#else
    return __expf(z * 0.6931471805599453f);
#endif
}

__device__ inline float frsq(float a) {
#if __has_builtin(__builtin_amdgcn_rsqf)
    return __builtin_amdgcn_rsqf(a);
#else
    return rsqrtf(a);
#endif
}

// tanh-form GELU via hw exp2/rcp
__device__ inline float gelu_f(float x) {
    float x2 = x * x;
    float z  = x * (2.302023914f + 0.1029480874f * x2);
    float e  = fast_exp2(z);
    float r  = __builtin_amdgcn_rcpf(e + 1.0f);
    return x - x * r;
}

// ---------------------------------------------------------------------------
// Pack W1/W2/W3 (fp32 [K][N]) into bf16 MFMA A-operand fragments, ks-major:
//  L1: [m][w(4)][ks(12)][ct(6)][lane(64)][8]  at 0       (294912 elems)
//  L2: [m][w(4)][ks(12)][ct(3)][lane(64)][8]  at 294912  (147456 elems)
//  L3: [m][ks(6)][ct(6)][lane(64)][8]         at 442368  (36864 elems)
// lane holds W[k = 32ks+8q+j][feat = base + l16]  (A[m=l16][k=8q+j])
// ---------------------------------------------------------------------------
__global__ __launch_bounds__(256) void pack_weights(
    const float* __restrict__ W1, const float* __restrict__ W2,
    const float* __restrict__ W3, ushort_t* __restrict__ wsp)
{
    int g = blockIdx.x * 256 + threadIdx.x;
    if (g >= 59904) return;
    const float* src; int N, n, kbase; ushort_t* dst;
    if (g < 36864) {                       // W1: K=384,N=384
        int s = g;
        int m = s / 18432, r = s % 18432;
        int w = r / 4608; r %= 4608;
        int ks = r / 384; r %= 384;
        int ct = r / 64; int lane = r % 64;
        int q = lane >> 4, l16 = lane & 15;
        src = W1 + m * 147456; N = 384;
        n = 96 * w + 16 * ct + l16;
        kbase = 32 * ks + 8 * q;
        dst = wsp + (size_t)g * 8;
    } else if (g < 55296) {                // W2: K=384,N=192
        int t = g - 36864;
        int m = t / 9216, r = t % 9216;
        int w = r / 2304; r %= 2304;
        int ks = r / 192; r %= 192;
        int ct = r / 64; int lane = r % 64;
        int q = lane >> 4, l16 = lane & 15;
        src = W2 + m * 73728; N = 192;
        n = 48 * w + 16 * ct + l16;
        kbase = 32 * ks + 8 * q;
        dst = wsp + 294912 + (size_t)t * 8;
    } else {                               // W3: K=192,N=96 -> [m][ks][ct][lane]
        int u = g - 55296;
        int m = u / 2304, r = u % 2304;
        int ks = r / 384; int r2 = r % 384;
        int ct = r2 / 64; int lane = r2 % 64;
        int q = lane >> 4, l16 = lane & 15;
        src = W3 + m * 18432; N = 96;
        n = 16 * ct + l16;
        kbase = 32 * ks + 8 * q;
        dst = wsp + 442368 + (size_t)u * 8;
    }
    ushortx8 o;
    #pragma unroll
    for (int j = 0; j < 8; ++j) o[j] = f2bf(src[(size_t)(kbase + j) * N + n]);
    *(ushortx8*)dst = o;
}

// ---------------------------------------------------------------------------
// Fused LN -> L1+GELU -> L2+GELU -> L3+GELU -> L4 -> log_softmax.
// Block = 48 rows (3 row-tiles), 256 thr (4 waves). 2 blocks/CU (LDS 78.7KB).
// Weight frags deep-prefetched (distance 4) from L2 into registers.
// ---------------------------------------------------------------------------
__global__ __launch_bounds__(256, 2) void fused_mlp(
    const float* __restrict__ x, const float* __restrict__ ln_g, const float* __restrict__ ln_b,
    const float* __restrict__ b1, const float* __restrict__ b2, const float* __restrict__ b3,
    const float* __restrict__ W4, const float* __restrict__ b4,
    const ushort_t* __restrict__ wsp, float* __restrict__ out)
{
    __shared__ __align__(16) ushort_t sA[18816];   // 48 x stride392 (reused 48 x stride200)
    __shared__ __align__(16) ushort_t sH[18816];   // 48 x stride392 (reused 48 x stride104)
    __shared__ __align__(16) float    sF[864];     // b1[0,384) b2[384,576) b3[576,672) W4T[672,864)

    const int tid = threadIdx.x;
    const int w = tid >> 6, lane = tid & 63, q = lane >> 4, l16 = lane & 15;
    const int bid = blockIdx.x;
    const int m  = bid / 2731;
    const int rb = bid % 2731;
    const size_t row0 = (size_t)m * 131072 + (size_t)rb * 48;
    const int valid = (rb == 2730) ? 32 : 48;      // last block per modality is ragged

    // ---- stage biases + W4^T ----
    {
        const float* pb1 = b1 + m * 384;
        const float* pb2 = b2 + m * 192;
        const float* pb3 = b3 + m * 96;
        const float* pW4 = W4 + m * 192;
        for (int i = tid; i < 384; i += 256) sF[i] = pb1[i];
        if (tid < 192) sF[384 + tid] = pb2[tid];
        if (tid < 96)  sF[576 + tid] = pb3[tid];
        if (tid < 192) sF[672 + (tid & 1) * 96 + (tid >> 1)] = pW4[tid]; // W4T[cl][k]
    }

    // ---- LayerNorm: 3 passes x 16 rows, 16 thr/row, 24 cols each ----
    {
        const int j = tid & 15, rsub = tid >> 4;   // rsub 0..15
        const floatx4* gv = (const floatx4*)(ln_g + m * 384);
        const floatx4* bv = (const floatx4*)(ln_b + m * 384);
        floatx4 ga[6], ca[6];
        #pragma unroll
        for (int i = 0; i < 6; ++i) { ga[i] = gv[6 * j + i]; ca[i] = bv[6 * j + i]; }
        #pragma unroll
        for (int p = 0; p < 3; ++p) {
            const int row = 16 * p + rsub;
            const floatx4* xv = (const floatx4*)(x + (row0 + row) * 384) + 6 * j;
            floatx4 v[6];
            if (row < valid) {
                #pragma unroll
                for (int i = 0; i < 6; ++i) v[i] = xv[i];
            } else {
                #pragma unroll
                for (int i = 0; i < 6; ++i) v[i] = floatx4{0.f, 0.f, 0.f, 0.f};
            }
            float s = 0.f, s2 = 0.f;
            #pragma unroll
            for (int i = 0; i < 6; ++i)
                #pragma unroll
                for (int e = 0; e < 4; ++e) { s += v[i][e]; s2 = fmaf(v[i][e], v[i][e], s2); }
            s  += __shfl_xor(s, 1);  s  += __shfl_xor(s, 2);
            s  += __shfl_xor(s, 4);  s  += __shfl_xor(s, 8);
            s2 += __shfl_xor(s2, 1); s2 += __shfl_xor(s2, 2);
            s2 += __shfl_xor(s2, 4); s2 += __shfl_xor(s2, 8);
            const float mu   = s * (1.0f / 384.0f);
            const float var  = fmaf(s2, 1.0f / 384.0f, -mu * mu);
            const float rstd = frsq(var + 1e-5f);
            #pragma unroll
            for (int h = 0; h < 3; ++h) {
                float y[8];
                #pragma unroll
                for (int e = 0; e < 4; ++e) {
                    y[e]     = (v[2*h][e]   - mu) * rstd * ga[2*h][e]   + ca[2*h][e];
                    y[4 + e] = (v[2*h+1][e] - mu) * rstd * ga[2*h+1][e] + ca[2*h+1][e];
                }
                uintx4 st = { pk_bf16(y[0], y[1]), pk_bf16(y[2], y[3]),
                              pk_bf16(y[4], y[5]), pk_bf16(y[6], y[7]) };
                *(uintx4*)&sA[row * 392 + 24 * j + 8 * h] = st;
            }
        }
    }

    // ---- L1 W-frag preload (distance 4) before barrier ----
    const bf16x8* Wv1 = (const bf16x8*)(wsp + (m * 4 + w) * 36864) + lane;
    bf16x8 wb1[4][6];
    #pragma unroll
    for (int s = 0; s < 4; ++s)
        #pragma unroll
        for (int c = 0; c < 6; ++c) wb1[s][c] = Wv1[(s * 6 + c) * 64];

    __syncthreads();

    const floatx4 vzero = {0.f, 0.f, 0.f, 0.f};

    // ---- Layer 1: wave w -> feats [96w,96w+96), 3 row-tiles ----
    floatx4 acc1[3][6];
    #pragma unroll
    for (int rt = 0; rt < 3; ++rt)
        #pragma unroll
        for (int ct = 0; ct < 6; ++ct) acc1[rt][ct] = vzero;
    #pragma unroll
    for (int ks = 0; ks < 12; ++ks) {
        bf16x8 a0 = *(const bf16x8*)&sA[l16        * 392 + 32 * ks + 8 * q];
        bf16x8 a1 = *(const bf16x8*)&sA[(16 + l16) * 392 + 32 * ks + 8 * q];
        bf16x8 a2 = *(const bf16x8*)&sA[(32 + l16) * 392 + 32 * ks + 8 * q];
        #pragma unroll
        for (int c = 0; c < 6; ++c) {
            acc1[0][c] = __builtin_amdgcn_mfma_f32_16x16x32_bf16(wb1[ks & 3][c], a0, acc1[0][c], 0, 0, 0);
            acc1[1][c] = __builtin_amdgcn_mfma_f32_16x16x32_bf16(wb1[ks & 3][c], a1, acc1[1][c], 0, 0, 0);
            acc1[2][c] = __builtin_amdgcn_mfma_f32_16x16x32_bf16(wb1[ks & 3][c], a2, acc1[2][c], 0, 0, 0);
        }
        if (ks < 8) {
            #pragma unroll
            for (int c = 0; c < 6; ++c) wb1[ks & 3][c] = Wv1[((ks + 4) * 6 + c) * 64];
        }
    }

    // ---- preload L2 W-frags (distance 4) before epilogue+barrier ----
    const bf16x8* Wv2 = (const bf16x8*)(wsp + 294912 + (m * 4 + w) * 18432) + lane;
    bf16x8 wb2[4][3];
    #pragma unroll
    for (int s = 0; s < 4; ++s)
        #pragma unroll
        for (int c = 0; c < 3; ++c) wb2[s][c] = Wv2[(s * 3 + c) * 64];

    // ---- L1 epilogue: bias + GELU -> sH stride 392 ----
    #pragma unroll
    for (int ct = 0; ct < 6; ++ct) {
        const int f = 96 * w + 16 * ct + 4 * q;
        const floatx4 bb = *(const floatx4*)&sF[f];
        #pragma unroll
        for (int rt = 0; rt < 3; ++rt) {
            float g0 = gelu_f(acc1[rt][ct][0] + bb[0]);
            float g1 = gelu_f(acc1[rt][ct][1] + bb[1]);
            float g2 = gelu_f(acc1[rt][ct][2] + bb[2]);
            float g3 = gelu_f(acc1[rt][ct][3] + bb[3]);
            uintx2 u = { pk_bf16(g0, g1), pk_bf16(g2, g3) };
            *(uintx2*)&sH[(16 * rt + l16) * 392 + f] = u;
        }
    }
    __syncthreads();

    // ---- Layer 2: wave w -> feats [48w,48w+48), 3 row-tiles ----
    floatx4 acc2[3][3];
    #pragma unroll
    for (int rt = 0; rt < 3; ++rt)
        #pragma unroll
        for (int ct = 0; ct < 3; ++ct) acc2[rt][ct] = vzero;
    #pragma unroll
    for (int ks = 0; ks < 12; ++ks) {
        bf16x8 a0 = *(const bf16x8*)&sH[l16        * 392 + 32 * ks + 8 * q];
        bf16x8 a1 = *(const bf16x8*)&sH[(16 + l16) * 392 + 32 * ks + 8 * q];
        bf16x8 a2 = *(const bf16x8*)&sH[(32 + l16) * 392 + 32 * ks + 8 * q];
        #pragma unroll
        for (int c = 0; c < 3; ++c) {
            acc2[0][c] = __builtin_amdgcn_mfma_f32_16x16x32_bf16(wb2[ks & 3][c], a0, acc2[0][c], 0, 0, 0);
            acc2[1][c] = __builtin_amdgcn_mfma_f32_16x16x32_bf16(wb2[ks & 3][c], a1, acc2[1][c], 0, 0, 0);
            acc2[2][c] = __builtin_amdgcn_mfma_f32_16x16x32_bf16(wb2[ks & 3][c], a2, acc2[2][c], 0, 0, 0);
        }
        if (ks < 8) {
            #pragma unroll
            for (int c = 0; c < 3; ++c) wb2[ks & 3][c] = Wv2[((ks + 4) * 3 + c) * 64];
        }
    }

    // ---- preload L3 W-frags (distance 3); only waves 0..2 compute L3 ----
    const bf16x8* Wv3 = (const bf16x8*)(wsp + 442368 + m * 18432) + lane;
    bf16x8 wb3[3][6];
    if (w < 3) {
        #pragma unroll
        for (int s = 0; s < 3; ++s)
            #pragma unroll
            for (int c = 0; c < 6; ++c) wb3[s][c] = Wv3[(s * 6 + c) * 64];
    }

    // ---- L2 epilogue -> sA stride 200 ----
    #pragma unroll
    for (int ct = 0; ct < 3; ++ct) {
        const int f = 48 * w + 16 * ct + 4 * q;
        const floatx4 bb = *(const floatx4*)&sF[384 + f];
        #pragma unroll
        for (int rt = 0; rt < 3; ++rt) {
            float g0 = gelu_f(acc2[rt][ct][0] + bb[0]);
            float g1 = gelu_f(acc2[rt][ct][1] + bb[1]);
            float g2 = gelu_f(acc2[rt][ct][2] + bb[2]);
            float g3 = gelu_f(acc2[rt][ct][3] + bb[3]);
            uintx2 u = { pk_bf16(g0, g1), pk_bf16(g2, g3) };
            *(uintx2*)&sA[(16 * rt + l16) * 200 + f] = u;
        }
    }
    __syncthreads();

    // ---- Layer 3: wave w (<3) -> row-tile w, all 96 feats ----
    if (w < 3) {
        floatx4 acc3[6];
        #pragma unroll
        for (int ct = 0; ct < 6; ++ct) acc3[ct] = vzero;
        #pragma unroll
        for (int ks = 0; ks < 6; ++ks) {
            bf16x8 a = *(const bf16x8*)&sA[(16 * w + l16) * 200 + 32 * ks + 8 * q];
            #pragma unroll
            for (int c = 0; c < 6; ++c)
                acc3[c] = __builtin_amdgcn_mfma_f32_16x16x32_bf16(wb3[ks % 3][c], a, acc3[c], 0, 0, 0);
            if (ks < 3) {
                #pragma unroll
                for (int c = 0; c < 6; ++c) wb3[ks % 3][c] = Wv3[((ks + 3) * 6 + c) * 64];
            }
        }
        // ---- L3 epilogue -> sH stride 104 ----
        #pragma unroll
        for (int ct = 0; ct < 6; ++ct) {
            const int f = 16 * ct + 4 * q;
            const floatx4 bb = *(const floatx4*)&sF[576 + f];
            float g0 = gelu_f(acc3[ct][0] + bb[0]);
            float g1 = gelu_f(acc3[ct][1] + bb[1]);
            float g2 = gelu_f(acc3[ct][2] + bb[2]);
            float g3 = gelu_f(acc3[ct][3] + bb[3]);
            uintx2 u = { pk_bf16(g0, g1), pk_bf16(g2, g3) };
            *(uintx2*)&sH[(16 * w + l16) * 104 + f] = u;
        }
    }
    __syncthreads();

    // ---- Layer 4: [48x96]@[96x2] + log_softmax; 192 threads, split-K ----
    if (tid < 192) {
        const int cl = tid & 1, kh = (tid >> 1) & 1, row = tid >> 2;   // row 0..47
        const float* wv = &sF[672 + cl * 96 + kh * 48];
        float p = 0.f;
        #pragma unroll
        for (int kk = 0; kk < 6; ++kk) {
            bf16x8 h = *(const bf16x8*)&sH[row * 104 + kh * 48 + kk * 8];
            const floatx4 wa = *(const floatx4*)&wv[kk * 8];
            const floatx4 wb = *(const floatx4*)&wv[kk * 8 + 4];
            p += (float)h[0] * wa[0] + (float)h[1] * wa[1] + (float)h[2] * wa[2] + (float)h[3] * wa[3]
               + (float)h[4] * wb[0] + (float)h[5] * wb[1] + (float)h[6] * wb[2] + (float)h[7] * wb[3];
        }
        p += __shfl_xor(p, 2);                  // combine K-halves
        const float logit = p + b4[m * 2 + cl];
        const float other = __shfl_xor(logit, 1);
        const float mx = fmaxf(logit, other);
        const float z  = __expf(logit - mx) + __expf(other - mx);
        const float res = logit - mx - __logf(z);
        if (kh == 0 && row < valid) out[(row0 + row) * 2 + cl] = res;
    }
}

extern "C" void kernel_launch(void* const* d_in, const int* in_sizes, int n_in,
                              void* d_out, int out_size, void* d_ws, size_t ws_size,
                              hipStream_t stream)
{
    const float* x    = (const float*)d_in[0];
    const float* ln_g = (const float*)d_in[1];
    const float* ln_b = (const float*)d_in[2];
    const float* W1   = (const float*)d_in[3];
    const float* b1   = (const float*)d_in[4];
    const float* W2   = (const float*)d_in[5];
    const float* b2   = (const float*)d_in[6];
    const float* W3   = (const float*)d_in[7];
    const float* b3   = (const float*)d_in[8];
    const float* W4   = (const float*)d_in[9];
    const float* b4   = (const float*)d_in[10];
    float* out = (float*)d_out;
    ushort_t* wsp = (ushort_t*)d_ws;   // 958,464 B packed bf16 weights

    pack_weights<<<234, 256, 0, stream>>>(W1, W2, W3, wsp);
    fused_mlp<<<5462, 256, 0, stream>>>(x, ln_g, ln_b, b1, b2, b3, W4, b4, wsp, out);
}